// Round 11
// baseline (82.775 us; speedup 1.0000x reference)
//
#include <hip/hip_runtime.h>

// YOLO decode, fused: feat13 [256,255,13,13] + feat26 [256,255,26,26]
//   -> out [256, 2535, 85] fp32   (2535 = 3*169 + 3*676)
//
// R11: push the confirmed granularity lever. W=208 tiles, 1024-thread blocks.
//  - Read segments 832 B, write streams 70.7 KB (vs 416 B / 35.4 KB in R10).
//  - Occupancy preserved: LDS 70.7 KB -> 2 blocks/CU x 16 waves = 32 waves/CU.
//  - head26 wave-autonomous (no barrier): 52 vf4-columns split across 16
//    waves (4,4,4,4,3x12); tail tile W=52: 1 col for waves 0-12. Full decode
//    during staging; wave-local lgkmcnt fence; store = pure LDS->global nt
//    copy (ds_read_b128 -> global_store_dwordx4).
//  - head13: full-plane tile W=169 -> one contiguous 57.5 KB write/block,
//    barrier'd block path, scalar pair-channel loads.

#define ROWS 2535
#define H26_BLOCKS (256 * 3 * 4)    // ceil(676/208) = 4 tiles (last W=52)
#define H13_BLOCKS (256 * 3)        // full-plane tile (W=169)

typedef float vf4 __attribute__((ext_vector_type(4)));

__device__ __forceinline__ float fsig(float v) {
    return __builtin_amdgcn_rcpf(1.0f + __expf(-v));
}

// ---- pure-copy store over [j_lo, j_hi) by one wave ----
__device__ __forceinline__ void copy_phase_wave(
    const float* __restrict__ lds, float* __restrict__ dst, int mis,
    int j_lo, int j_hi)
{
    const int lane = threadIdx.x & 63;
    const int kk  = (4 - ((mis + j_lo) & 3)) & 3;   // scalars to 16B boundary
    const int qlo = j_lo + kk;
    const int nq  = (j_hi - qlo) >> 2;

    if (lane < kk && j_lo + lane < j_hi)
        __builtin_nontemporal_store(lds[mis + j_lo + lane], dst + j_lo + lane);
    for (int q = lane; q < nq; q += 64) {
        int j0 = qlo + q * 4;
        const vf4 v = *(const vf4*)(lds + mis + j0);    // 16B-aligned b128
        __builtin_nontemporal_store(v, (vf4*)(dst + j0));
    }
    for (int j = qlo + nq * 4 + lane; j < j_hi; j += 64)
        __builtin_nontemporal_store(lds[mis + j], dst + j);
}

// ---- pure-copy store, block-wide (head13, after __syncthreads) ----
__device__ __forceinline__ void copy_phase_block(
    const float* __restrict__ lds, float* __restrict__ dst, int mis, int n)
{
    const int t  = threadIdx.x;
    const int kk = (4 - mis) & 3;
    const int nq = (n - kk) >> 2;
    if (t < kk)
        __builtin_nontemporal_store(lds[mis + t], dst + t);
    for (int q = t; q < nq; q += 1024) {
        int j0 = q * 4 + kk;
        const vf4 v = *(const vf4*)(lds + mis + j0);
        __builtin_nontemporal_store(v, (vf4*)(dst + j0));
    }
    for (int j = kk + nq * 4 + t; j < n; j += 1024)
        __builtin_nontemporal_store(lds[mis + j], dst + j);
}

__device__ __forceinline__ void head26_body(
    const float* __restrict__ f, float* __restrict__ out, float* __restrict__ lds,
    int bid)
{
    constexpr int GG = 676, TPP = 4;
    const int tile = bid % TPP;       // constexpr divisors -> magic mul
    const int ba   = bid / TPP;
    const int a    = ba % 3;
    const int b    = ba / 3;
    const int s0   = tile * 208;      // s0 % 26 == 0 (208 = 8*26)
    const int W    = (GG - s0 < 208) ? (GG - s0) : 208;   // 208 or 52
    const int C4   = W >> 2;          // 52 or 13 vf4-columns

    const float aw = (a == 0) ? 10.f : (a == 1) ? 23.f : 37.f;
    const float ah = (a == 0) ? 14.f : (a == 1) ? 27.f : 58.f;

    const float* __restrict__ src = f + (size_t)(b * 255 + a * 85) * GG + s0;
    float* __restrict__ dst = out + ((size_t)b * ROWS + 507 + (size_t)a * GG + s0) * 85;
    const int mis  = (int)(((size_t)dst >> 2) & 3);
    const int wave = threadIdx.x >> 6;     // 0..15
    const int lane = threadIdx.x & 63;

    // column split across 16 waves:
    //   C4=52: waves 0-3 -> 4 cols, waves 4-15 -> 3 cols (16 + 36 = 52)
    //   C4=13: waves 0-12 -> 1 col, waves 13-15 -> 0
    int lo, ncol;
    if (C4 == 52) { ncol = (wave < 4) ? 4 : 3;
                    lo   = (wave < 4) ? wave * 4 : 16 + (wave - 4) * 3; }
    else          { ncol = (wave < 13) ? 1 : 0;
                    lo   = wave; }
    const int nitems = 85 * ncol;     // <= 340 -> <= 6 rounds of 64 lanes

    #define DECOMP(i, c, w4r)                                   \
        do { if (ncol == 4)      { c = (i) >> 2; w4r = (i) & 3; }\
             else if (ncol == 3) { c = (i) / 3;  w4r = (i) - c * 3; }\
             else                { c = (i);      w4r = 0; } } while (0)

    // ---- batched loads ----
    vf4 V[6];
    #pragma unroll
    for (int r = 0; r < 6; ++r) {
        int i = lane + r * 64;
        if (i < nitems) {
            int c, w4r; DECOMP(i, c, w4r);
            V[r] = *(const vf4*)(src + (size_t)c * GG + (lo + w4r) * 4);
        }
    }

    // ---- decode + LDS write (FINAL values; stride 85 = odd bank step) ----
    #pragma unroll
    for (int r = 0; r < 6; ++r) {
        int i = lane + r * 64;
        if (i < nitems) {
            int c, w4r; DECOMP(i, c, w4r);
            const int wb   = (lo + w4r) * 4;            // spatial w of V[r].x
            const int base = mis + wb * 85 + c;
            const vf4 v = V[r];
            if (c >= 4) {
                lds[base]       = fsig(v.x);
                lds[base + 85]  = fsig(v.y);
                lds[base + 170] = fsig(v.z);
                lds[base + 255] = fsig(v.w);
            } else if (c == 0) {
                #pragma unroll
                for (int e = 0; e < 4; ++e) {
                    int w = wb + e;                     // 0..207
                    int k26 = w / 26;                   // const div
                    int gx  = w - k26 * 26;
                    lds[base + e * 85] = (fsig(v[e]) + (float)gx) * 16.0f;
                }
            } else if (c == 1) {
                #pragma unroll
                for (int e = 0; e < 4; ++e) {
                    int w = wb + e;
                    int k26 = w / 26;
                    int gy  = tile * 8 + k26;           // s0/26 = tile*8
                    lds[base + e * 85] = (fsig(v[e]) + (float)gy) * 16.0f;
                }
            } else {
                #pragma unroll
                for (int e = 0; e < 4; ++e)
                    lds[base + e * 85] = __expf(v[e]) * ((c == 2) ? aw : ah);
            }
        }
    }
    #undef DECOMP

    // wave-local LDS fence (no block barrier)
    asm volatile("s_waitcnt lgkmcnt(0)" ::: "memory");
    __builtin_amdgcn_sched_barrier(0);

    copy_phase_wave(lds, dst, mis, lo * 340, (lo + ncol) * 340);
}

__device__ __forceinline__ void head13_body(
    const float* __restrict__ f, float* __restrict__ out, float* __restrict__ lds,
    int bid)
{
    constexpr int GG = 169;
    const int a = bid % 3;
    const int b = bid / 3;

    const float aw = (a == 0) ? 81.f : (a == 1) ? 135.f : 344.f;
    const float ah = (a == 0) ? 82.f : (a == 1) ? 169.f : 319.f;

    const float* __restrict__ src = f + (size_t)(b * 255 + a * 85) * GG;
    float* __restrict__ dst = out + ((size_t)b * ROWS + (size_t)a * GG) * 85;
    const int mis = (int)(((size_t)dst >> 2) & 3);
    const int t = threadIdx.x;

    // ---- load phase: 42 pairs x 169 w = 7098 dual items, 7 rounds ----
    float A[7], B[7], Lv;
    #pragma unroll
    for (int k = 0; k < 7; ++k) {
        int i = t + k * 1024;
        if (k < 6 || i < 7098) {
            int p = i / 169;          // const div
            int w = i - p * 169;
            const float* s = src + (size_t)(2 * p) * GG + w;
            A[k] = s[0];
            B[k] = s[GG];
        }
    }
    const bool okL = t < GG;                  // leftover channel c=84
    if (okL) Lv = src[(size_t)84 * GG + t];

    // ---- decode + write phase (FINAL values) ----
    #pragma unroll
    for (int k = 0; k < 7; ++k) {
        int i = t + k * 1024;
        if (k < 6 || i < 7098) {
            int p = i / 169;
            int w = i - p * 169;
            int base = mis + w * 85 + 2 * p;
            if (p >= 2) {
                lds[base]     = fsig(A[k]);
                lds[base + 1] = fsig(B[k]);
            } else if (p == 0) {
                int t13 = w / 13;             // const div
                int gx  = w - t13 * 13;
                lds[base]     = (fsig(A[k]) + (float)gx) * 32.0f;
                lds[base + 1] = (fsig(B[k]) + (float)t13) * 32.0f;
            } else {
                lds[base]     = __expf(A[k]) * aw;
                lds[base + 1] = __expf(B[k]) * ah;
            }
        }
    }
    if (okL) lds[mis + t * 85 + 84] = fsig(Lv);
    __syncthreads();

    copy_phase_block(lds, dst, mis, GG * 85);
}

__global__ __launch_bounds__(1024, 8) void yolo_fused(
    const float* __restrict__ f13, const float* __restrict__ f26,
    float* __restrict__ out)
{
    __shared__ __align__(16) float lds[208 * 85 + 4];  // 70.7 KB -> 2 blk/CU
    const int bid = blockIdx.x;
    if (bid < H26_BLOCKS) head26_body(f26, out, lds, bid);
    else                  head13_body(f13, out, lds, bid - H26_BLOCKS);
}

extern "C" void kernel_launch(void* const* d_in, const int* in_sizes, int n_in,
                              void* d_out, int out_size, void* d_ws, size_t ws_size,
                              hipStream_t stream) {
    const float* f13 = (const float*)d_in[0];
    const float* f26 = (const float*)d_in[1];
    float* out = (float*)d_out;
    yolo_fused<<<H26_BLOCKS + H13_BLOCKS, 1024, 0, stream>>>(f13, f26, out);
}

// Round 12
// 69.841 us; speedup vs baseline: 1.1852x; 1.1852x over previous
//
#include <hip/hip_runtime.h>

// YOLO decode, fused: feat13 [256,255,13,13] + feat26 [256,255,26,26]
//   -> out [256, 2535, 85] fp32   (2535 = 3*169 + 3*676)
//
// R12 = R10 (best: 78.6 us) + bijective chunked XCD swizzle.
//  - R10 proven: W=104 tiles, 512-thread blocks, 35.4 KB LDS (4 blk/CU,
//    32 waves), full decode during staging, wave-autonomous head26 (no
//    barrier, wave-local lgkmcnt fence), pure LDS->global nt-copy store.
//  - NEW: blockIdx swizzle bid = (w%8)*864 + w/8 (grid 6912 % 8 == 0 ->
//    bijective). Consecutive ORIGINAL bids (= adjacent spatial tiles of the
//    same (b,a) plane, which share seam cache lines: segments are 16B- not
//    128B-aligned) now run on the SAME XCD at dispatch slots 8 apart ->
//    seam lines hit in L2 instead of being re-fetched from HBM after L3
//    eviction (R10 FETCH 140.8 MB vs R11's 122.2 with 2x tiles; seam-dup
//    arithmetic ~ 6 seams x 85 ch x 128 B x 768 planes ~ 50 MB matches).

#define ROWS 2535
#define H26_BLOCKS (256 * 3 * 7)    // ceil(676/104) = 7 tiles (last W=52)
#define H13_BLOCKS (256 * 3 * 2)    // ceil(169/104) = 2 tiles (last W=65)
#define NWG (H26_BLOCKS + H13_BLOCKS)   // 6912, % 8 == 0

typedef float vf4 __attribute__((ext_vector_type(4)));

__device__ __forceinline__ float fsig(float v) {
    return __builtin_amdgcn_rcpf(1.0f + __expf(-v));
}

// ---- pure-copy store over [j_lo, j_hi) by one wave ----
__device__ __forceinline__ void copy_phase_wave(
    const float* __restrict__ lds, float* __restrict__ dst, int mis,
    int j_lo, int j_hi)
{
    const int lane = threadIdx.x & 63;
    const int kk  = (4 - ((mis + j_lo) & 3)) & 3;   // scalars to 16B boundary
    const int qlo = j_lo + kk;
    const int nq  = (j_hi - qlo) >> 2;

    if (lane < kk && j_lo + lane < j_hi)
        __builtin_nontemporal_store(lds[mis + j_lo + lane], dst + j_lo + lane);
    for (int q = lane; q < nq; q += 64) {
        int j0 = qlo + q * 4;
        const vf4 v = *(const vf4*)(lds + mis + j0);    // 16B-aligned b128
        __builtin_nontemporal_store(v, (vf4*)(dst + j0));
    }
    for (int j = qlo + nq * 4 + lane; j < j_hi; j += 64)
        __builtin_nontemporal_store(lds[mis + j], dst + j);
}

// ---- pure-copy store, block-wide (head13, after __syncthreads) ----
__device__ __forceinline__ void copy_phase_block(
    const float* __restrict__ lds, float* __restrict__ dst, int mis, int n)
{
    const int t  = threadIdx.x;
    const int kk = (4 - mis) & 3;
    const int nq = (n - kk) >> 2;
    if (t < kk)
        __builtin_nontemporal_store(lds[mis + t], dst + t);
    for (int q = t; q < nq; q += 512) {
        int j0 = q * 4 + kk;
        const vf4 v = *(const vf4*)(lds + mis + j0);
        __builtin_nontemporal_store(v, (vf4*)(dst + j0));
    }
    for (int j = kk + nq * 4 + t; j < n; j += 512)
        __builtin_nontemporal_store(lds[mis + j], dst + j);
}

__device__ __forceinline__ void head26_body(
    const float* __restrict__ f, float* __restrict__ out, float* __restrict__ lds,
    int bid)
{
    constexpr int GG = 676, TPP = 7;
    const int tile = bid % TPP;       // constexpr divisors -> magic mul
    const int ba   = bid / TPP;
    const int a    = ba % 3;
    const int b    = ba / 3;
    const int s0   = tile * 104;      // s0 % 26 == 0
    const int W    = (GG - s0 < 104) ? (GG - s0) : 104;   // 104 or 52
    const int C4   = W >> 2;          // 26 or 13 vf4-columns

    const float aw = (a == 0) ? 10.f : (a == 1) ? 23.f : 37.f;
    const float ah = (a == 0) ? 14.f : (a == 1) ? 27.f : 58.f;

    const float* __restrict__ src = f + (size_t)(b * 255 + a * 85) * GG + s0;
    float* __restrict__ dst = out + ((size_t)b * ROWS + 507 + (size_t)a * GG + s0) * 85;
    const int mis  = (int)(((size_t)dst >> 2) & 3);
    const int wave = threadIdx.x >> 6;
    const int lane = threadIdx.x & 63;

    // column split across 8 waves:
    //   C4=26: waves 0,1 -> 4 cols; waves 2..7 -> 3 cols
    //   C4=13: waves 0..4 -> 2 cols; waves 5..7 -> 1 col
    int lo, nw4;
    if (C4 == 26) { nw4 = (wave < 2) ? 4 : 3;
                    lo  = (wave < 2) ? wave * 4 : 8 + (wave - 2) * 3; }
    else          { nw4 = (wave < 5) ? 2 : 1;
                    lo  = (wave < 5) ? wave * 2 : 10 + (wave - 5); }
    const int nitems = 85 * nw4;      // <= 340 -> <= 6 rounds of 64 lanes

    // c-major item decomposition (wave-uniform divisor selection)
    #define DECOMP(i, c, w4r)                                   \
        do { if (nw4 == 4)      { c = (i) >> 2; w4r = (i) & 3; }\
             else if (nw4 == 3) { c = (i) / 3;  w4r = (i) - c * 3; }\
             else if (nw4 == 2) { c = (i) >> 1; w4r = (i) & 1; }\
             else               { c = (i);      w4r = 0; } } while (0)

    // ---- batched loads ----
    vf4 V[6];
    #pragma unroll
    for (int r = 0; r < 6; ++r) {
        int i = lane + r * 64;
        if (i < nitems) {
            int c, w4r; DECOMP(i, c, w4r);
            V[r] = *(const vf4*)(src + (size_t)c * GG + (lo + w4r) * 4);
        }
    }

    // ---- decode + LDS write (FINAL values; stride 85 = odd bank step) ----
    #pragma unroll
    for (int r = 0; r < 6; ++r) {
        int i = lane + r * 64;
        if (i < nitems) {
            int c, w4r; DECOMP(i, c, w4r);
            const int wb   = (lo + w4r) * 4;            // spatial w of V[r].x
            const int base = mis + wb * 85 + c;
            const vf4 v = V[r];
            if (c >= 4) {
                lds[base]       = fsig(v.x);
                lds[base + 85]  = fsig(v.y);
                lds[base + 170] = fsig(v.z);
                lds[base + 255] = fsig(v.w);
            } else if (c == 0) {
                #pragma unroll
                for (int e = 0; e < 4; ++e) {
                    int w = wb + e;
                    int k26 = w / 26;                   // const div, 0..3
                    int gx  = w - k26 * 26;
                    lds[base + e * 85] = (fsig(v[e]) + (float)gx) * 16.0f;
                }
            } else if (c == 1) {
                #pragma unroll
                for (int e = 0; e < 4; ++e) {
                    int w = wb + e;
                    int k26 = w / 26;
                    int gy  = tile * 4 + k26;           // s0/26 = tile*4
                    lds[base + e * 85] = (fsig(v[e]) + (float)gy) * 16.0f;
                }
            } else {
                #pragma unroll
                for (int e = 0; e < 4; ++e)
                    lds[base + e * 85] = __expf(v[e]) * ((c == 2) ? aw : ah);
            }
        }
    }
    #undef DECOMP

    // wave-local LDS fence (no block barrier)
    asm volatile("s_waitcnt lgkmcnt(0)" ::: "memory");
    __builtin_amdgcn_sched_barrier(0);

    copy_phase_wave(lds, dst, mis, lo * 340, (lo + nw4) * 340);
}

__device__ __forceinline__ void head13_body(
    const float* __restrict__ f, float* __restrict__ out, float* __restrict__ lds,
    int bid)
{
    constexpr int GG = 169, TPP = 2;
    const int tile = bid % TPP;
    const int ba   = bid / TPP;
    const int a    = ba % 3;
    const int b    = ba / 3;
    const int s0   = tile * 104;      // s0 % 13 == 0
    const int W    = (GG - s0 < 104) ? (GG - s0) : 104;   // 104, 65

    const float aw = (a == 0) ? 81.f : (a == 1) ? 135.f : 344.f;
    const float ah = (a == 0) ? 82.f : (a == 1) ? 169.f : 319.f;

    const float* __restrict__ src = f + (size_t)(b * 255 + a * 85) * GG;
    float* __restrict__ dst = out + ((size_t)b * ROWS + (size_t)a * GG + s0) * 85;
    const int mis = (int)(((size_t)dst >> 2) & 3);
    const int t = threadIdx.x;

    // ---- load phase: 42 pairs x 104 w-slots = 4368 items, 9 rounds ----
    float A[9], B[9], Lv;
    #pragma unroll
    for (int k = 0; k < 9; ++k) {
        int i = t + k * 512;
        int p = i / 104;              // const div
        int w = i - p * 104;
        if ((k < 8 || i < 4368) && (w < W)) {
            const float* s = src + (size_t)(2 * p) * GG + s0 + w;
            A[k] = s[0];
            B[k] = s[GG];
        }
    }
    const bool okL = t < W;                   // leftover channel c=84
    if (okL) Lv = src[(size_t)84 * GG + s0 + t];

    // ---- decode + write phase (FINAL values) ----
    #pragma unroll
    for (int k = 0; k < 9; ++k) {
        int i = t + k * 512;
        int p = i / 104;
        int w = i - p * 104;
        if ((k < 8 || i < 4368) && (w < W)) {
            int base = mis + w * 85 + 2 * p;
            if (p >= 2) {
                lds[base]     = fsig(A[k]);
                lds[base + 1] = fsig(B[k]);
            } else if (p == 0) {
                int t13 = w / 13;             // const div, 0..7
                int gx  = w - t13 * 13;
                int gy  = tile * 8 + t13;     // s0/13 = tile*8
                lds[base]     = (fsig(A[k]) + (float)gx) * 32.0f;
                lds[base + 1] = (fsig(B[k]) + (float)gy) * 32.0f;
            } else {
                lds[base]     = __expf(A[k]) * aw;
                lds[base + 1] = __expf(B[k]) * ah;
            }
        }
    }
    if (okL) lds[mis + t * 85 + 84] = fsig(Lv);
    __syncthreads();

    copy_phase_block(lds, dst, mis, W * 85);
}

__global__ __launch_bounds__(512, 8) void yolo_fused(
    const float* __restrict__ f13, const float* __restrict__ f26,
    float* __restrict__ out)
{
    __shared__ __align__(16) float lds[104 * 85 + 4];  // 35.4 KB -> 4 blk/CU
    // Bijective chunked XCD swizzle (NWG % 8 == 0): consecutive original
    // bids (adjacent tiles of one plane) -> same XCD, dispatch slots 8 apart.
    const int w   = blockIdx.x;
    const int bid = (w & 7) * (NWG / 8) + (w >> 3);
    if (bid < H26_BLOCKS) head26_body(f26, out, lds, bid);
    else                  head13_body(f13, out, lds, bid - H26_BLOCKS);
}

extern "C" void kernel_launch(void* const* d_in, const int* in_sizes, int n_in,
                              void* d_out, int out_size, void* d_ws, size_t ws_size,
                              hipStream_t stream) {
    const float* f13 = (const float*)d_in[0];
    const float* f26 = (const float*)d_in[1];
    float* out = (float*)d_out;
    yolo_fused<<<NWG, 512, 0, stream>>>(f13, f26, out);
}